// Round 1
// baseline (584.618 us; speedup 1.0000x reference)
//
#include <hip/hip_runtime.h>
#include <hip/hip_bf16.h>
#include <stdint.h>

// Problem constants (fixed by the reference)
#define BB 4096      // batch
#define NN 1024      // generator dim
#define PP 32        // n_params
#define EE 16        // expand ratio
#define NC (NN*EE)   // 16384 output columns

typedef __bf16 bf16x8 __attribute__((ext_vector_type(8)));
typedef float  f32x4  __attribute__((ext_vector_type(4)));

// async global->LDS, 16B per lane. LDS dest must be wave-uniform base; HW
// writes lane i at base + i*16 (guide §5 / m97 / m104).
__device__ __forceinline__ void gl2lds16(const void* g, void* l) {
  __builtin_amdgcn_global_load_lds(
      (const __attribute__((address_space(1))) void*)g,
      (__attribute__((address_space(3))) void*)l,
      16, 0, 0);
}

// ---------------------------------------------------------------------------
// K1: x fp32 -> bf16
__global__ __launch_bounds__(256) void cvt_x_kernel(
    const float* __restrict__ x, __hip_bfloat16* __restrict__ xb) {
  size_t i4 = (size_t)blockIdx.x * 256 + threadIdx.x;   // float4 index
  float4 v = ((const float4*)x)[i4];
  union { __hip_bfloat16 h[4]; ushort4 u; } pk;
  pk.h[0] = __float2bfloat16(v.x);
  pk.h[1] = __float2bfloat16(v.y);
  pk.h[2] = __float2bfloat16(v.z);
  pk.h[3] = __float2bfloat16(v.w);
  *(ushort4*)(xb + i4 * 4) = pk.u;
}

// ---------------------------------------------------------------------------
// K2: Gt[(i*EE+e)*NN + j] = sum_p params[p,e] * T[p, i*NN + j]   (fp32 math,
// bf16 store). One block per i-row; each thread handles 4 consecutive j.
// p-loop unrolled x4 so 4 independent 16B loads are in flight per wave
// (was 1 -> latency-bound at the 4MB p-stride; 64KB/CU in flight covers the
// ~24.6 GB/s/CU BW share per Little's law).
__global__ __launch_bounds__(256) void make_filters(
    const float* __restrict__ params,     // [PP][EE]
    const float* __restrict__ T,          // [PP][NN*NN]
    __hip_bfloat16* __restrict__ Gt) {    // [NC][NN]
  const int tid = threadIdx.x;
  const int i = blockIdx.x;               // 0..NN-1
  const int j = tid * 4;
  const float4* Tv = (const float4*)T;
  const size_t qv = ((size_t)i * NN + j) >> 2;   // float4 index into one p-slab
  const size_t SLABQ = (size_t)NN * NN / 4;

  float acc[EE][4];
#pragma unroll
  for (int e = 0; e < EE; ++e) {
    acc[e][0] = 0.f; acc[e][1] = 0.f; acc[e][2] = 0.f; acc[e][3] = 0.f;
  }

  for (int p = 0; p < PP; p += 4) {
    // issue all four loads before any use -> 4 VMEM ops in flight
    float4 t0 = Tv[(size_t)(p + 0) * SLABQ + qv];
    float4 t1 = Tv[(size_t)(p + 1) * SLABQ + qv];
    float4 t2 = Tv[(size_t)(p + 2) * SLABQ + qv];
    float4 t3 = Tv[(size_t)(p + 3) * SLABQ + qv];
#pragma unroll
    for (int e = 0; e < EE; ++e) {
      float w0 = params[(p + 0) * EE + e];   // uniform -> s_load
      float w1 = params[(p + 1) * EE + e];
      float w2 = params[(p + 2) * EE + e];
      float w3 = params[(p + 3) * EE + e];
      acc[e][0] += w0 * t0.x; acc[e][1] += w0 * t0.y;
      acc[e][2] += w0 * t0.z; acc[e][3] += w0 * t0.w;
      acc[e][0] += w1 * t1.x; acc[e][1] += w1 * t1.y;
      acc[e][2] += w1 * t1.z; acc[e][3] += w1 * t1.w;
      acc[e][0] += w2 * t2.x; acc[e][1] += w2 * t2.y;
      acc[e][2] += w2 * t2.z; acc[e][3] += w2 * t2.w;
      acc[e][0] += w3 * t3.x; acc[e][1] += w3 * t3.y;
      acc[e][2] += w3 * t3.z; acc[e][3] += w3 * t3.w;
    }
  }

#pragma unroll
  for (int e = 0; e < EE; ++e) {
    union { __hip_bfloat16 h[4]; ushort4 u; } pk;
    pk.h[0] = __float2bfloat16(acc[e][0]);
    pk.h[1] = __float2bfloat16(acc[e][1]);
    pk.h[2] = __float2bfloat16(acc[e][2]);
    pk.h[3] = __float2bfloat16(acc[e][3]);
    *(ushort4*)&Gt[((size_t)i * EE + e) * NN + j] = pk.u;
  }
}

// ---------------------------------------------------------------------------
// K3: C[b, c] = swish( sum_j A[b,j] * Bt[c,j] )
// A  = x_bf16  [BB][NN] row-major
// Bt = Gt      [NC][NN] row-major (K-major, so A- and B-fragments load alike)
// 128x128 tile, BK=32, 256 threads = 4 waves in 2x2, 4x4 mfma 16x16x32 each.
// MFMA operands SWAPPED (Bt-frag as arg0) so each lane's 4 acc regs are 4
// consecutive N-columns -> packed dwordx4 C-stores (64 dword -> 16 dwordx4).
// XCD-aware block swizzle: each XCD owns a 16-wide bn column block x all bm,
// so each 256KB B-tile is reused 32x from that XCD's L2.
__global__ __launch_bounds__(256) void gemm_swish(
    const __hip_bfloat16* __restrict__ A,
    const __hip_bfloat16* __restrict__ Bt,
    float* __restrict__ C) {
  __shared__ __hip_bfloat16 As[128 * 32];   // 8 KB, unpadded (global_load_lds)
  __shared__ __hip_bfloat16 Bs[128 * 32];   // 8 KB

  const int tid  = threadIdx.x;

  // T1: bijective XCD swizzle (4096 blocks % 8 == 0)
  const int flat = blockIdx.y * 128 + blockIdx.x;   // 0..4095
  const int xcd  = flat & 7;
  const int idx  = flat >> 3;                       // 0..511 within XCD
  const int bm   = idx & 31;                        // sweep M inside one bn
  const int bn   = xcd * 16 + (idx >> 5);           // 16 bn-columns per XCD

  const int wv   = tid >> 6;                // wave 0..3
  const int lane = tid & 63;

  // staging addressing: thread t -> row t/4, elem col (t&3)*8 (16 B)
  const int ldrow = tid >> 2;
  const int ldcol = (tid & 3) * 8;
  const __hip_bfloat16* a0 = A  + ((size_t)bm * 128 + ldrow) * NN + ldcol;
  const __hip_bfloat16* b0 = Bt + ((size_t)bn * 128 + ldrow) * NN + ldcol;
  char* asDst = (char*)As + wv * 1024;      // wave-uniform LDS base
  char* bsDst = (char*)Bs + wv * 1024;

  const int wm   = (wv >> 1) * 64;
  const int wn   = (wv & 1) * 64;
  const int lrow = lane & 15;
  const int lk   = (lane >> 4) * 8;

  f32x4 acc[4][4] = {};

  for (int kt = 0; kt < NN / 32; ++kt) {
    const int k0 = kt * 32;
    __syncthreads();                        // previous iter done reading LDS
    gl2lds16(a0 + k0,            asDst);
    gl2lds16(a0 + 64 * NN + k0,  asDst + 4096);
    gl2lds16(b0 + k0,            bsDst);
    gl2lds16(b0 + 64 * NN + k0,  bsDst + 4096);
    __syncthreads();                        // drains vmcnt -> tiles visible

    bf16x8 af[4], bfr[4];
#pragma unroll
    for (int mt = 0; mt < 4; ++mt)
      af[mt] = *(const bf16x8*)&As[(wm + mt * 16 + lrow) * 32 + lk];
#pragma unroll
    for (int nt = 0; nt < 4; ++nt)
      bfr[nt] = *(const bf16x8*)&Bs[(wn + nt * 16 + lrow) * 32 + lk];

    // arg0 = B-fragment: D "row" dim = N side, D "col" dim = M side.
    // Frag layouts for arg0/arg1 are lane-identical (both K-major), so the
    // swap only changes the C/D interpretation, not the loads.
#pragma unroll
    for (int mt = 0; mt < 4; ++mt)
#pragma unroll
      for (int nt = 0; nt < 4; ++nt)
        acc[mt][nt] = __builtin_amdgcn_mfma_f32_16x16x32_bf16(
            bfr[nt], af[mt], acc[mt][nt], 0, 0, 0);
  }

  // epilogue: with swapped operands, C/D layout (col=lane&15, row=(lane>>4)*4+r)
  // maps to: output row (M) = lane&15, output col (N) = (lane>>4)*4 + r.
  // -> 4 consecutive output columns per lane: pack into one dwordx4 store.
  const size_t row0 = (size_t)bm * 128 + wm + (lane & 15);
  const size_t col0 = (size_t)bn * 128 + wn + (lane >> 4) * 4;
#pragma unroll
  for (int mt = 0; mt < 4; ++mt) {
    const size_t rbase = (row0 + mt * 16) * (size_t)NC;
#pragma unroll
    for (int nt = 0; nt < 4; ++nt) {
      f32x4 v = acc[mt][nt];
      f32x4 s;
#pragma unroll
      for (int r = 0; r < 4; ++r) {
        float o = v[r];
        // swish via v_rcp_f32 (approx rcp; absmax budget 0.03 >> rcp error)
        s[r] = o * __builtin_amdgcn_rcpf(1.0f + __expf(-o));
      }
      *(f32x4*)&C[rbase + col0 + nt * 16] = s;
    }
  }
}

// ---------------------------------------------------------------------------
extern "C" void kernel_launch(void* const* d_in, const int* in_sizes, int n_in,
                              void* d_out, int out_size, void* d_ws, size_t ws_size,
                              hipStream_t stream) {
  const float* x      = (const float*)d_in[0];   // [BB][NN]
  const float* params = (const float*)d_in[1];   // [PP][EE]
  const float* T      = (const float*)d_in[2];   // [PP][NN][NN]
  float* out = (float*)d_out;                    // [BB][NN][EE]

  __hip_bfloat16* Gt = (__hip_bfloat16*)d_ws;                       // 32 MB
  __hip_bfloat16* xb = (__hip_bfloat16*)((char*)d_ws + (size_t)NC * NN * 2); // 8 MB

  cvt_x_kernel<<<(BB * NN / 4) / 256, 256, 0, stream>>>(x, xb);
  make_filters<<<NN, 256, 0, stream>>>(params, T, Gt);
  gemm_swish<<<dim3(NC / 128, BB / 128), 256, 0, stream>>>(xb, Gt, out);
}

// Round 2
// 471.484 us; speedup vs baseline: 1.2400x; 1.2400x over previous
//
#include <hip/hip_runtime.h>
#include <hip/hip_bf16.h>
#include <stdint.h>

// Problem constants (fixed by the reference)
#define BB 4096      // batch
#define NN 1024      // generator dim
#define PP 32        // n_params
#define EE 16        // expand ratio
#define NC (NN*EE)   // 16384 output columns

// GEMM tile geometry (256x256, BK=64, 8 waves)
#define BM 256
#define BN 256
#define BK 64
#define NT (NN/BK)   // 16 K-tiles

typedef __bf16 bf16x8 __attribute__((ext_vector_type(8)));
typedef float  f32x4  __attribute__((ext_vector_type(4)));

// async global->LDS, 16B per lane. LDS dest must be wave-uniform base; HW
// writes lane i at base + i*16 (guide §5 / m97 / m104).
__device__ __forceinline__ void gl2lds16(const void* g, void* l) {
  __builtin_amdgcn_global_load_lds(
      (const __attribute__((address_space(1))) void*)g,
      (__attribute__((address_space(3))) void*)l,
      16, 0, 0);
}

// ---------------------------------------------------------------------------
// K1: x fp32 -> bf16
__global__ __launch_bounds__(256) void cvt_x_kernel(
    const float* __restrict__ x, __hip_bfloat16* __restrict__ xb) {
  size_t i4 = (size_t)blockIdx.x * 256 + threadIdx.x;   // float4 index
  float4 v = ((const float4*)x)[i4];
  union { __hip_bfloat16 h[4]; ushort4 u; } pk;
  pk.h[0] = __float2bfloat16(v.x);
  pk.h[1] = __float2bfloat16(v.y);
  pk.h[2] = __float2bfloat16(v.z);
  pk.h[3] = __float2bfloat16(v.w);
  *(ushort4*)(xb + i4 * 4) = pk.u;
}

// ---------------------------------------------------------------------------
// K2: Gt[(i*EE+e)*NN + j] = sum_p params[p,e] * T[p, i*NN + j]   (fp32 math,
// bf16 store). Unchanged from round 1 (passed; bounded < 258us by top-5).
__global__ __launch_bounds__(256) void make_filters(
    const float* __restrict__ params,     // [PP][EE]
    const float* __restrict__ T,          // [PP][NN*NN]
    __hip_bfloat16* __restrict__ Gt) {    // [NC][NN]
  const int tid = threadIdx.x;
  const int i = blockIdx.x;               // 0..NN-1
  const int j = tid * 4;
  const float4* Tv = (const float4*)T;
  const size_t qv = ((size_t)i * NN + j) >> 2;   // float4 index into one p-slab
  const size_t SLABQ = (size_t)NN * NN / 4;

  float acc[EE][4];
#pragma unroll
  for (int e = 0; e < EE; ++e) {
    acc[e][0] = 0.f; acc[e][1] = 0.f; acc[e][2] = 0.f; acc[e][3] = 0.f;
  }

#pragma unroll 1
  for (int p = 0; p < PP; p += 4) {
    float4 t0 = Tv[(size_t)(p + 0) * SLABQ + qv];
    float4 t1 = Tv[(size_t)(p + 1) * SLABQ + qv];
    float4 t2 = Tv[(size_t)(p + 2) * SLABQ + qv];
    float4 t3 = Tv[(size_t)(p + 3) * SLABQ + qv];
#pragma unroll
    for (int e = 0; e < EE; ++e) {
      float w0 = params[(p + 0) * EE + e];
      float w1 = params[(p + 1) * EE + e];
      float w2 = params[(p + 2) * EE + e];
      float w3 = params[(p + 3) * EE + e];
      acc[e][0] += w0 * t0.x; acc[e][1] += w0 * t0.y;
      acc[e][2] += w0 * t0.z; acc[e][3] += w0 * t0.w;
      acc[e][0] += w1 * t1.x; acc[e][1] += w1 * t1.y;
      acc[e][2] += w1 * t1.z; acc[e][3] += w1 * t1.w;
      acc[e][0] += w2 * t2.x; acc[e][1] += w2 * t2.y;
      acc[e][2] += w2 * t2.z; acc[e][3] += w2 * t2.w;
      acc[e][0] += w3 * t3.x; acc[e][1] += w3 * t3.y;
      acc[e][2] += w3 * t3.z; acc[e][3] += w3 * t3.w;
    }
  }

#pragma unroll
  for (int e = 0; e < EE; ++e) {
    union { __hip_bfloat16 h[4]; ushort4 u; } pk;
    pk.h[0] = __float2bfloat16(acc[e][0]);
    pk.h[1] = __float2bfloat16(acc[e][1]);
    pk.h[2] = __float2bfloat16(acc[e][2]);
    pk.h[3] = __float2bfloat16(acc[e][3]);
    *(ushort4*)&Gt[((size_t)i * EE + e) * NN + j] = pk.u;
  }
}

// ---------------------------------------------------------------------------
// K3: C[b, c] = swish( sum_j A[b,j] * Bt[c,j] )
// 256x256 tile, BK=64, 512 threads = 8 waves (2M x 4N), wave-tile 128x64,
// 8x4 frags of mfma_16x16x32. LDS double-buffered [2 slots][A,B][256*64]
// = 128 KB. T3-minimum schedule: stage(n+1) issued BEFORE compute(n);
// __syncthreads() per tile gives the m97-proven vmcnt-drain semantics.
//
// T2 bank-conflict swizzle (rule #21: both-sides-or-neither):
//   - LDS dest stays LINEAR (global_load_lds requirement, m104)
//   - staging SOURCE col-chunk pre-swizzled: chunk_src = (lane&7) ^ (row&7)
//   - every ds_read applies chunk ^= (row&7)
// Rows are 128 B (64 bf16) -> exact m214 geometry where linear layout is a
// 16-way conflict on ds_read_b128 (+89% fix there).
// Natural block order (NO XCD swizzle -- round-1 A/B showed +84% FETCH).
__global__ __launch_bounds__(512, 2) void gemm_swish(
    const __hip_bfloat16* __restrict__ A,
    const __hip_bfloat16* __restrict__ Bt,
    float* __restrict__ C) {
  __shared__ __hip_bfloat16 lds[2][2][BM * BK];   // [slot][A=0/B=1], 128 KB

  const int tid  = threadIdx.x;
  const int wv   = tid >> 6;                // 0..7
  const int lane = tid & 63;
  const int bn   = blockIdx.x;              // 0..63
  const int bm   = blockIdx.y;              // 0..15

  // ---- staging coordinates (per 8KB issue: 64 rows x 128 B) ----
  // wave wv covers rows [issue*64 + wv*8, +8); lane -> row wv*8+(lane>>3),
  // source chunk pre-swizzled by row&7 (= lane>>3 since bases are %8==0).
  const int srow = wv * 8 + (lane >> 3);
  const int scol = ((lane & 7) ^ (lane >> 3)) * 8;   // bf16 elems
  const __hip_bfloat16* aSrc = A  + ((size_t)bm * BM + srow) * NN + scol;
  const __hip_bfloat16* bSrc = Bt + ((size_t)bn * BN + srow) * NN + scol;

  // ---- compute coordinates ----
  const int wm   = (wv >> 2) * 128;         // wave M offset in tile
  const int wn   = (wv & 3) * 64;           // wave N offset in tile
  const int lrow = lane & 15;               // frag row within 16
  const int g    = lane >> 4;               // k-group 0..3
  const int xr   = lane & 7;                // = row&7 for every frag row

  f32x4 acc[8][4] = {};

  auto stage = [&](int n_) {
    const int s_  = n_ & 1;
    const int k0_ = n_ * BK;
    char* la = (char*)&lds[s_][0][0] + wv * 1024;
    char* lb = (char*)&lds[s_][1][0] + wv * 1024;
#pragma unroll
    for (int i = 0; i < 4; ++i) {
      gl2lds16(aSrc + (size_t)i * 64 * NN + k0_, la + i * 8192);
      gl2lds16(bSrc + (size_t)i * 64 * NN + k0_, lb + i * 8192);
    }
  };

  stage(0);
  __syncthreads();

  for (int n = 0; n < NT; ++n) {
    if (n + 1 < NT) stage(n + 1);           // issue early: lands under compute

    const int s = n & 1;
#pragma unroll
    for (int kk = 0; kk < 2; ++kk) {
      bf16x8 af[8], bf[4];
#pragma unroll
      for (int mt = 0; mt < 8; ++mt) {
        const int row = wm + mt * 16 + lrow;
        const int ch  = (kk * 4 + g) ^ xr;          // swizzled chunk
        af[mt] = *(const bf16x8*)&lds[s][0][row * 64 + ch * 8];
      }
#pragma unroll
      for (int nt = 0; nt < 4; ++nt) {
        const int row = wn + nt * 16 + lrow;
        const int ch  = (kk * 4 + g) ^ xr;
        bf[nt] = *(const bf16x8*)&lds[s][1][row * 64 + ch * 8];
      }
#pragma unroll
      for (int mt = 0; mt < 8; ++mt)
#pragma unroll
        for (int nt = 0; nt < 4; ++nt)
          acc[mt][nt] = __builtin_amdgcn_mfma_f32_16x16x32_bf16(
              af[mt], bf[nt], acc[mt][nt], 0, 0, 0);
    }

    __syncthreads();   // drains vmcnt(0): tile n+1 landed; all done reading n
  }

  // epilogue: C/D layout col=lane&15, row=(lane>>4)*4+r (m89/m91, round-0
  // verified). Each store instr: 4 rows x 64 B contiguous segments.
  const size_t row0 = (size_t)bm * BM + wm + (lane >> 4) * 4;
  const size_t col0 = (size_t)bn * BN + wn + (lane & 15);
#pragma unroll
  for (int mt = 0; mt < 8; ++mt) {
#pragma unroll
    for (int nt = 0; nt < 4; ++nt) {
      const size_t col = col0 + nt * 16;
#pragma unroll
      for (int r = 0; r < 4; ++r) {
        float o = acc[mt][nt][r];
        float s = o * __builtin_amdgcn_rcpf(1.0f + __expf(-o));  // swish
        C[(row0 + mt * 16 + r) * NC + col] = s;
      }
    }
  }
}

// ---------------------------------------------------------------------------
extern "C" void kernel_launch(void* const* d_in, const int* in_sizes, int n_in,
                              void* d_out, int out_size, void* d_ws, size_t ws_size,
                              hipStream_t stream) {
  const float* x      = (const float*)d_in[0];   // [BB][NN]
  const float* params = (const float*)d_in[1];   // [PP][EE]
  const float* T      = (const float*)d_in[2];   // [PP][NN][NN]
  float* out = (float*)d_out;                    // [BB][NN][EE]

  __hip_bfloat16* Gt = (__hip_bfloat16*)d_ws;                       // 32 MB
  __hip_bfloat16* xb = (__hip_bfloat16*)((char*)d_ws + (size_t)NC * NN * 2); // 8 MB

  cvt_x_kernel<<<(BB * NN / 4) / 256, 256, 0, stream>>>(x, xb);
  make_filters<<<NN, 256, 0, stream>>>(params, T, Gt);
  gemm_swish<<<dim3(NC / BN, BB / BM), 512, 0, stream>>>(xb, Gt, out);
}

// Round 3
// 462.476 us; speedup vs baseline: 1.2641x; 1.0195x over previous
//
#include <hip/hip_runtime.h>
#include <hip/hip_bf16.h>
#include <stdint.h>

// Problem constants (fixed by the reference)
#define BB 4096      // batch
#define NN 1024      // generator dim
#define PP 32        // n_params
#define EE 16        // expand ratio
#define NC (NN*EE)   // 16384 output columns

// GEMM tile geometry (256x256, BK=64, 8 waves)
#define BM 256
#define BN 256
#define BK 64
#define NT (NN/BK)   // 16 K-tiles

typedef __bf16 bf16x8 __attribute__((ext_vector_type(8)));
typedef float  f32x4  __attribute__((ext_vector_type(4)));

// async global->LDS, 16B per lane. LDS dest must be wave-uniform base; HW
// writes lane i at base + i*16 (guide §5 / m97 / m104).
__device__ __forceinline__ void gl2lds16(const void* g, void* l) {
  __builtin_amdgcn_global_load_lds(
      (const __attribute__((address_space(1))) void*)g,
      (__attribute__((address_space(3))) void*)l,
      16, 0, 0);
}

// ---------------------------------------------------------------------------
// K1: x fp32 -> bf16
__global__ __launch_bounds__(256) void cvt_x_kernel(
    const float* __restrict__ x, __hip_bfloat16* __restrict__ xb) {
  size_t i4 = (size_t)blockIdx.x * 256 + threadIdx.x;   // float4 index
  float4 v = ((const float4*)x)[i4];
  union { __hip_bfloat16 h[4]; ushort4 u; } pk;
  pk.h[0] = __float2bfloat16(v.x);
  pk.h[1] = __float2bfloat16(v.y);
  pk.h[2] = __float2bfloat16(v.z);
  pk.h[3] = __float2bfloat16(v.w);
  *(ushort4*)(xb + i4 * 4) = pk.u;
}

// ---------------------------------------------------------------------------
// K2: Gt[(i*EE+e)*NN + j] = sum_p params[p,e] * T[p, i*NN + j]
// Round-3 theory: latency-starved (achieved ~1.2 TB/s on a read-once
// stream). Chunk-8 load issue: 8 independent float4 loads in flight per
// thread (128 B) -> 16 waves/CU x 8 KB = 128 KB in flight per CU, >> the
// ~9.2 KB Little's-law requirement at 900-cyc HBM latency. VGPR ~110 so
// occupancy stays 16 waves/CU.
__global__ __launch_bounds__(256) void make_filters(
    const float* __restrict__ params,     // [PP][EE]
    const float* __restrict__ T,          // [PP][NN*NN]
    __hip_bfloat16* __restrict__ Gt) {    // [NC][NN]
  const int tid = threadIdx.x;
  const int i = blockIdx.x;               // 0..NN-1
  const int j = tid * 4;
  const float4* Tv = (const float4*)T;
  const size_t qv = ((size_t)i * NN + j) >> 2;   // float4 index into one p-slab
  const size_t SLABQ = (size_t)NN * NN / 4;

  float acc[EE][4];
#pragma unroll
  for (int e = 0; e < EE; ++e) {
    acc[e][0] = 0.f; acc[e][1] = 0.f; acc[e][2] = 0.f; acc[e][3] = 0.f;
  }

#pragma unroll 1
  for (int p0 = 0; p0 < PP; p0 += 8) {
    float4 t[8];
#pragma unroll
    for (int u = 0; u < 8; ++u)          // 8 loads issued back-to-back
      t[u] = Tv[(size_t)(p0 + u) * SLABQ + qv];
#pragma unroll
    for (int u = 0; u < 8; ++u) {
#pragma unroll
      for (int e = 0; e < EE; ++e) {
        float w = params[(p0 + u) * EE + e];   // uniform -> s_load
        acc[e][0] += w * t[u].x; acc[e][1] += w * t[u].y;
        acc[e][2] += w * t[u].z; acc[e][3] += w * t[u].w;
      }
    }
  }

#pragma unroll
  for (int e = 0; e < EE; ++e) {
    union { __hip_bfloat16 h[4]; ushort4 u; } pk;
    pk.h[0] = __float2bfloat16(acc[e][0]);
    pk.h[1] = __float2bfloat16(acc[e][1]);
    pk.h[2] = __float2bfloat16(acc[e][2]);
    pk.h[3] = __float2bfloat16(acc[e][3]);
    *(ushort4*)&Gt[((size_t)i * EE + e) * NN + j] = pk.u;
  }
}

// ---------------------------------------------------------------------------
// K3: C[b, c] = swish( sum_j A[b,j] * Bt[c,j] )
// 256x256 tile, BK=64, 512 threads = 8 waves (2M x 4N), wave-tile 128x64.
// Round-3 change: intra-tile 2-phase split. Per kk-phase:
//   {stage half of tile n+1 (4 gl2lds) + issue this phase's 12 ds_reads}
//   -> s_barrier (wave alignment) -> setprio(1) 32 MFMA setprio(0).
// End-of-tile __syncthreads() keeps the proven buffer discipline (stage
// only ever writes buf s^1; the intra-tile barriers are correctness-
// neutral). T5 needs a phase-split schedule to arbitrate (m218b).
//
// T2 bank-conflict swizzle unchanged (rule #21 both-sides):
//   LDS dest linear; source chunk pre-swizzled (lane&7)^(lane>>3);
//   ds_read chunk ^= (row&7).
__global__ __launch_bounds__(512, 2) void gemm_swish(
    const __hip_bfloat16* __restrict__ A,
    const __hip_bfloat16* __restrict__ Bt,
    float* __restrict__ C) {
  __shared__ __hip_bfloat16 lds[2][2][BM * BK];   // [slot][A=0/B=1], 128 KB

  const int tid  = threadIdx.x;
  const int wv   = tid >> 6;                // 0..7
  const int lane = tid & 63;
  const int bn   = blockIdx.x;              // 0..63
  const int bm   = blockIdx.y;              // 0..15

  // ---- staging coordinates (per 8KB issue: 64 rows x 128 B) ----
  const int srow = wv * 8 + (lane >> 3);
  const int scol = ((lane & 7) ^ (lane >> 3)) * 8;   // pre-swizzled source col
  const __hip_bfloat16* aSrc = A  + ((size_t)bm * BM + srow) * NN + scol;
  const __hip_bfloat16* bSrc = Bt + ((size_t)bn * BN + srow) * NN + scol;

  // ---- compute coordinates ----
  const int wm   = (wv >> 2) * 128;         // wave M offset in tile
  const int wn   = (wv & 3) * 64;           // wave N offset in tile
  const int lrow = lane & 15;               // frag row within 16
  const int g    = lane >> 4;               // k-group 0..3
  const int xr   = lane & 7;                // = row&7 for every frag row

  f32x4 acc[8][4] = {};

  // stage one operand-half (A: h=0, B: h=1) of tile n_ into slot n_&1
  auto stage_half = [&](int n_, int h_) {
    const int s_  = n_ & 1;
    const int k0_ = n_ * BK;
    const __hip_bfloat16* src = h_ ? bSrc : aSrc;
    char* dst = (char*)&lds[s_][h_][0] + wv * 1024;
#pragma unroll
    for (int i = 0; i < 4; ++i)
      gl2lds16(src + (size_t)i * 64 * NN + k0_, dst + i * 8192);
  };

  stage_half(0, 0);
  stage_half(0, 1);
  __syncthreads();

  for (int n = 0; n < NT; ++n) {
    const int s = n & 1;
#pragma unroll
    for (int kk = 0; kk < 2; ++kk) {
      // phase: stage half of next tile, then this phase's fragment reads
      if (n + 1 < NT) stage_half(n + 1, kk);

      bf16x8 af[8], bf[4];
      const int ch = (kk * 4 + g) ^ xr;               // swizzled chunk
#pragma unroll
      for (int mt = 0; mt < 8; ++mt)
        af[mt] = *(const bf16x8*)&lds[s][0][(wm + mt * 16 + lrow) * 64 + ch * 8];
#pragma unroll
      for (int nt = 0; nt < 4; ++nt)
        bf[nt] = *(const bf16x8*)&lds[s][1][(wn + nt * 16 + lrow) * 64 + ch * 8];

      __builtin_amdgcn_s_barrier();                   // align waves at MFMA
      __builtin_amdgcn_s_setprio(1);
#pragma unroll
      for (int mt = 0; mt < 8; ++mt)
#pragma unroll
        for (int nt = 0; nt < 4; ++nt)
          acc[mt][nt] = __builtin_amdgcn_mfma_f32_16x16x32_bf16(
              af[mt], bf[nt], acc[mt][nt], 0, 0, 0);
      __builtin_amdgcn_s_setprio(0);
    }

    __syncthreads();   // drains vmcnt(0): tile n+1 landed; all done reading n
  }

  // epilogue: C/D layout col=lane&15, row=(lane>>4)*4+r (m89/m91)
  const size_t row0 = (size_t)bm * BM + wm + (lane >> 4) * 4;
  const size_t col0 = (size_t)bn * BN + wn + (lane & 15);
#pragma unroll
  for (int mt = 0; mt < 8; ++mt) {
#pragma unroll
    for (int nt = 0; nt < 4; ++nt) {
      const size_t col = col0 + nt * 16;
#pragma unroll
      for (int r = 0; r < 4; ++r) {
        float o = acc[mt][nt][r];
        float s = o * __builtin_amdgcn_rcpf(1.0f + __expf(-o));  // swish
        C[(row0 + mt * 16 + r) * NC + col] = s;
      }
    }
  }
}

// ---------------------------------------------------------------------------
extern "C" void kernel_launch(void* const* d_in, const int* in_sizes, int n_in,
                              void* d_out, int out_size, void* d_ws, size_t ws_size,
                              hipStream_t stream) {
  const float* x      = (const float*)d_in[0];   // [BB][NN]
  const float* params = (const float*)d_in[1];   // [PP][EE]
  const float* T      = (const float*)d_in[2];   // [PP][NN][NN]
  float* out = (float*)d_out;                    // [BB][NN][EE]

  __hip_bfloat16* Gt = (__hip_bfloat16*)d_ws;                       // 32 MB
  __hip_bfloat16* xb = (__hip_bfloat16*)((char*)d_ws + (size_t)NC * NN * 2); // 8 MB

  cvt_x_kernel<<<(BB * NN / 4) / 256, 256, 0, stream>>>(x, xb);
  make_filters<<<NN, 256, 0, stream>>>(params, T, Gt);
  gemm_swish<<<dim3(NC / BN, BB / BM), 512, 0, stream>>>(xb, Gt, out);
}